// Round 3
// baseline (169.008 us; speedup 1.0000x reference)
//
#include <hip/hip_runtime.h>

// Problem constants (MultiAttention_61340722921598)
#define BATCH 2
#define SEQ   2048
#define DMODEL 1024
#define NHEADS 16
#define HDIM   64
#define WINDOW 128
#define ROWS  (BATCH * SEQ)          // 4096

typedef __bf16 bf16x8 __attribute__((ext_vector_type(8)));
typedef __bf16 bf16x4 __attribute__((ext_vector_type(4)));
typedef float  f32x4  __attribute__((ext_vector_type(4)));

// async global->LDS, 16B per lane; LDS dest = wave-uniform base + lane*16
__device__ __forceinline__ void async_load16(const __bf16* g, __bf16* l) {
    __builtin_amdgcn_global_load_lds(
        (const __attribute__((address_space(1))) unsigned int*)g,
        (__attribute__((address_space(3))) unsigned int*)l, 16, 0, 0);
}

// ---------------------------------------------------------------------------
// fp32 -> bf16 conversion of X and the 4 weights; tail range computes the
// RoPE cos/sin table (exact libm sincosf, matching the fp32 reference).
// ---------------------------------------------------------------------------
__global__ __launch_bounds__(256) void convert_bf16(
    const float* __restrict__ X,
    const float* __restrict__ Wq, const float* __restrict__ Wk,
    const float* __restrict__ Wv, const float* __restrict__ Wo,
    __bf16* __restrict__ Xbf, __bf16* __restrict__ Wbf,
    float* __restrict__ ct, float* __restrict__ st)
{
    const int XN = ROWS * DMODEL / 4;     // 1,048,576 groups
    const int WN = DMODEL * DMODEL / 4;   // 262,144 per W
    const int TOT = XN + 4 * WN;          // 2,097,152
    int idx = blockIdx.x * blockDim.x + threadIdx.x;

    if (idx < TOT) {
        const float* src;
        __bf16* dst;
        if (idx < XN) {
            src = X + (size_t)idx * 4;
            dst = Xbf + (size_t)idx * 4;
        } else {
            int rel = idx - XN;
            int w = rel / WN;
            int off = rel - w * WN;
            const float* Wp = (w == 0) ? Wq : (w == 1) ? Wk : (w == 2) ? Wv : Wo;
            src = Wp + (size_t)off * 4;
            dst = Wbf + (size_t)rel * 4;
        }
        float4 v = *(const float4*)src;
        bf16x4 o;
        o[0] = (__bf16)v.x; o[1] = (__bf16)v.y; o[2] = (__bf16)v.z; o[3] = (__bf16)v.w;
        *(bf16x4*)dst = o;
    } else if (idx < TOT + SEQ * 32) {
        int k = idx - TOT;
        int t = k >> 5, d = k & 31;
        float ang = (float)t * expf(-(float)d * 0.28782313662425572f); // ln(1e4)/32
        float s, c;
        sincosf(ang, &s, &c);
        ct[k] = c; st[k] = s;
    }
}

// ---------------------------------------------------------------------------
// QKV projection: 256x256 tile, BK=32, 4-slab LDS ring with COUNTED vmcnt
// (T3+T4).  A = Xbf [4096x1024], B = Wq|Wk|Wv rows [3072x1024],
// C[m][n] = sum_k A[m][k] B[n][k].  512 threads = 8 waves (2M x 4N),
// per-wave output 128x64 (acc[8][4]).  LDS: As[4][256*32] + Bs[4][256*32]
// = 128 KB.  Staging runs 3 slabs ahead of compute; the per-iteration wait
// is vmcnt(8) = (4 loads/slab) x (2 newer slabs in flight), placed ~6
// phases after issue -> near-free (never drains to 0 in the main loop).
// XOR chunk swizzle = the r4-verified map (0 conflicts measured):
// LDS row r slot s holds global chunk s^((r>>1)&3); staging lane->row
// lane>>2, slot lane&3, src chunk (lane&3)^((lane>>3)&3); read slot
// 8*((lane>>4)^((frow>>1)&3)).  Phases: {reads -> bar -> setprio(1) +
// 16 MFMA + setprio(0) -> bar} x2 per slab.  Ring-slot reuse is always
// separated by a barrier (slab t+3 overwrites slab t-1's slot, whose last
// reads completed before iter t-1's closing barrier).
// A/B-frag: elem[row=lane&15][k=(lane>>4)*8+j]; C/D: col=lane&15,
// row=(lane>>4)*4+reg (verified m89, rounds 2-8).
// ---------------------------------------------------------------------------
#define RAW_BAR __builtin_amdgcn_s_barrier()
#define VM8     asm volatile("s_waitcnt vmcnt(8)" ::: "memory")
#define VM4     asm volatile("s_waitcnt vmcnt(4)" ::: "memory")
#define VM0     asm volatile("s_waitcnt vmcnt(0)" ::: "memory")
#define CFENCE  asm volatile("" ::: "memory")
#define MFMA16(a, b, c) __builtin_amdgcn_mfma_f32_16x16x32_bf16(a, b, c, 0, 0, 0)

__global__ __launch_bounds__(512, 2) void gemm_qkv_ring(
    const __bf16* __restrict__ X, const __bf16* __restrict__ Wbf,
    __bf16* __restrict__ Qb, __bf16* __restrict__ Kb, __bf16* __restrict__ Vb,
    const float* __restrict__ ct, const float* __restrict__ st)
{
    __shared__ __bf16 As[4 * 256 * 32];   // 64 KB, 4 ring slabs
    __shared__ __bf16 Bs[4 * 256 * 32];   // 64 KB

    const int tid  = threadIdx.x;
    const int lane = tid & 63;
    const int wv   = tid >> 6;           // 0..7
    const int wr   = wv >> 2;            // 0..1 (M)
    const int wc   = wv & 3;             // 0..3 (N)

    // grid 12x16 = 192 blocks; XCD-chunked swizzle (192 % 8 == 0, bijective)
    int id = blockIdx.x + 12 * blockIdx.y;
    int tt = (id & 7) * 24 + (id >> 3);
    const int xb = tt % 12, yb = tt / 12;
    const int m0 = yb * 256;
    const int n0 = xb * 256;             // never crosses a 1024 boundary

    // ---- staging maps (r4-verified): wave stripe = 32 rows (2 calls of 16)
    const int srow  = lane >> 2;                       // 0..15
    const int schk  = 8 * ((lane & 3) ^ ((lane >> 3) & 3));
    const int abase = wv * 32;                         // stripe base row
    const __bf16* gA = X   + (size_t)(m0 + abase + srow) * DMODEL + schk;
    const __bf16* gB = Wbf + (size_t)(n0 + abase + srow) * DMODEL + schk;

#define STAGE(RING, T) do {                                    \
    __bf16* la = As + (RING) * 8192 + abase * 32;              \
    __bf16* lb = Bs + (RING) * 8192 + abase * 32;              \
    const int kk = (T) * 32;                                   \
    async_load16(gA + kk,             la);                     \
    async_load16(gA + kk + 16 * DMODEL, la + 512);             \
    async_load16(gB + kk,             lb);                     \
    async_load16(gB + kk + 16 * DMODEL, lb + 512);             \
} while (0)

    // ---- fragment read maps (r4-verified)
    const int frow = lane & 15;
    const int hi   = lane >> 4;
    const int fsw  = 8 * (hi ^ ((frow >> 1) & 3));
    const int aoff = (wr * 128 + frow) * 32 + fsw;   // + i*512 per i-tile
    const int boff = (wc * 64 + frow) * 32 + fsw;    // + j*512 per j-tile

    f32x4 acc[8][4];
#pragma unroll
    for (int i = 0; i < 8; ++i)
#pragma unroll
        for (int j = 0; j < 4; ++j) {
            acc[i][j][0] = 0.f; acc[i][j][1] = 0.f;
            acc[i][j][2] = 0.f; acc[i][j][3] = 0.f;
        }

#define ROW4(I, AF)                                                     \
    acc[I][0] = MFMA16(AF, bfr0, acc[I][0]);                            \
    acc[I][1] = MFMA16(AF, bfr1, acc[I][1]);                            \
    acc[I][2] = MFMA16(AF, bfr2, acc[I][2]);                            \
    acc[I][3] = MFMA16(AF, bfr3, acc[I][3]);

// one slab = 2 phases; STAGE issues next+3 slab; VM_STMT is the counted wait
#define ITER(RING, STAGE_STMT, VM_STMT) do {                            \
    const __bf16* Asl = As + (RING) * 8192;                             \
    const __bf16* Bsl = Bs + (RING) * 8192;                             \
    STAGE_STMT;                                                         \
    bf16x8 bfr0 = *(const bf16x8*)(Bsl + boff);                         \
    bf16x8 bfr1 = *(const bf16x8*)(Bsl + boff + 512);                   \
    bf16x8 bfr2 = *(const bf16x8*)(Bsl + boff + 1024);                  \
    bf16x8 bfr3 = *(const bf16x8*)(Bsl + boff + 1536);                  \
    bf16x8 af0 = *(const bf16x8*)(Asl + aoff);                          \
    bf16x8 af1 = *(const bf16x8*)(Asl + aoff + 512);                    \
    bf16x8 af2 = *(const bf16x8*)(Asl + aoff + 1024);                   \
    bf16x8 af3 = *(const bf16x8*)(Asl + aoff + 1536);                   \
    CFENCE; RAW_BAR; CFENCE;                                            \
    __builtin_amdgcn_s_setprio(1);                                      \
    ROW4(0, af0) ROW4(1, af1) ROW4(2, af2) ROW4(3, af3)                 \
    __builtin_amdgcn_s_setprio(0);                                      \
    CFENCE; RAW_BAR; CFENCE;                                            \
    bf16x8 af4 = *(const bf16x8*)(Asl + aoff + 2048);                   \
    bf16x8 af5 = *(const bf16x8*)(Asl + aoff + 2560);                   \
    bf16x8 af6 = *(const bf16x8*)(Asl + aoff + 3072);                   \
    bf16x8 af7 = *(const bf16x8*)(Asl + aoff + 3584);                   \
    CFENCE; RAW_BAR; CFENCE;                                            \
    __builtin_amdgcn_s_setprio(1);                                      \
    ROW4(4, af4) ROW4(5, af5) ROW4(6, af6) ROW4(7, af7)                 \
    __builtin_amdgcn_s_setprio(0);                                      \
    VM_STMT;                                                            \
    CFENCE; RAW_BAR; CFENCE;                                            \
} while (0)

    // prologue: stage slabs 0,1,2; wait slab 0 (2 newer = 8 loads in flight)
    STAGE(0, 0); STAGE(1, 1); STAGE(2, 2);
    VM8;
    CFENCE; RAW_BAR; CFENCE;

    // main loop: slabs 0..27, staging 3 ahead, counted vmcnt(8) per slab
    for (int t = 0; t < 28; t += 4) {
        ITER(0, STAGE(3, t + 3), VM8);
        ITER(1, STAGE(0, t + 4), VM8);
        ITER(2, STAGE(1, t + 5), VM8);
        ITER(3, STAGE(2, t + 6), VM8);
    }
    // tail: slab 28 stages slab 31; then drain schedule 8 -> 4 -> 0
    ITER(0, STAGE(3, 31), VM8);
    ITER(1, (void)0, VM4);
    ITER(2, (void)0, VM0);
    ITER(3, (void)0, (void)0);

    // ---- epilogue: RoPE (+Q scale) and write to Q/K/V (z uniform per block)
    const int z = n0 >> 10;
    __bf16* Cz = (z == 0) ? Qb : (z == 1) ? Kb : Vb;
    const int ncol = n0 & 1023;
#pragma unroll
    for (int i = 0; i < 8; ++i) {
#pragma unroll
        for (int r = 0; r < 4; ++r) {
            int row  = m0 + wr * 128 + i * 16 + hi * 4 + r;
            int tpos = row & (SEQ - 1);
            if (z <= 1) {
#pragma unroll
                for (int j = 0; j < 2; ++j) {
                    int dd = j * 16 + frow;
                    float c = ct[tpos * 32 + dd];
                    float s = st[tpos * 32 + dd];
                    float v0 = acc[i][j][r], v1 = acc[i][j + 2][r];
                    float n0v = v0 * c - v1 * s;
                    float n1v = v1 * c + v0 * s;
                    if (z == 0) { n0v *= 0.125f; n1v *= 0.125f; }
                    acc[i][j][r] = n0v; acc[i][j + 2][r] = n1v;
                }
            }
#pragma unroll
            for (int j = 0; j < 4; ++j) {
                int col = ncol + wc * 64 + j * 16 + frow;
                Cz[(size_t)row * DMODEL + col] = (__bf16)acc[i][j][r];
            }
        }
    }
#undef ITER
#undef ROW4
#undef STAGE
}

// ---------------------------------------------------------------------------
// Round-0 BK=128 2-barrier MFMA GEMM body (verified) — used for out-proj.
// C[m][n] = sum_k A[m][k] * B[n][k]. 4 x 32-halves, XOR chunk swizzle.
// ---------------------------------------------------------------------------
template<int TM, int TN>
__device__ __forceinline__ void gemm_mfma_body(
    const __bf16* __restrict__ A, const __bf16* __restrict__ B,
    void* __restrict__ Cout, const float* __restrict__ bias,
    const float* __restrict__ ct, const float* __restrict__ st,
    int mode, int N, int K, int m0, int n0)
{
    constexpr bool SQ = (TN == 128);          // 2x2 wave layout
    constexpr int NI = SQ ? 4 : (TM / 64);    // 16-row i-tiles per wave
    constexpr int NAC = TM / 64;              // A staging calls per wave/half
    constexpr int NBC = TN / 64;              // B staging calls per wave/half
    __shared__ __bf16 As[4][TM * 32];
    __shared__ __bf16 Bs[4][TN * 32];

    const int tid  = threadIdx.x;
    const int lane = tid & 63;
    const int wv   = tid >> 6;
    const int wrow = SQ ? (wv >> 1) * 64 : wv * (TM / 4);
    const int wcol = SQ ? (wv & 1) * 64 : 0;

    const int srow = lane >> 2;
    const int schk = (lane & 3) ^ ((lane >> 3) & 3);
    const int arbase = wv * (TM / 4);
    const int brbase = wv * (TN / 4);

    const __bf16* gA0 = A + (size_t)(m0 + arbase + srow) * K + 8 * schk;
    const __bf16* gA1 = gA0 + (size_t)16 * K;
    const __bf16* gB0 = B + (size_t)(n0 + brbase + srow) * K + 8 * schk;
    const __bf16* gB1 = gB0 + (size_t)16 * K;

    const int frow = lane & 15;
    const int fsw  = 8 * ((lane >> 4) ^ ((frow >> 1) & 3));

    f32x4 acc[NI][4];
#pragma unroll
    for (int i = 0; i < NI; ++i)
#pragma unroll
        for (int j = 0; j < 4; ++j) {
            acc[i][j][0] = 0.f; acc[i][j][1] = 0.f;
            acc[i][j][2] = 0.f; acc[i][j][3] = 0.f;
        }

    for (int k0 = 0; k0 < K; k0 += 128) {
        __syncthreads();                 // prior iter's LDS reads complete
#pragma unroll
        for (int h = 0; h < 4; ++h) {
            async_load16(gA0 + k0 + 32 * h, As[h] + arbase * 32);
            if (NAC == 2)
                async_load16(gA1 + k0 + 32 * h, As[h] + (arbase + 16) * 32);
            async_load16(gB0 + k0 + 32 * h, Bs[h] + brbase * 32);
            if (NBC == 2)
                async_load16(gB1 + k0 + 32 * h, Bs[h] + (brbase + 16) * 32);
        }
        __syncthreads();                 // drains vmcnt: staging visible

#pragma unroll
        for (int h = 0; h < 4; ++h) {
            bf16x8 afr[NI], bfr[4];
#pragma unroll
            for (int i = 0; i < NI; ++i)
                afr[i] = *(const bf16x8*)(As[h] + (wrow + 16 * i + frow) * 32 + fsw);
#pragma unroll
            for (int j = 0; j < 4; ++j)
                bfr[j] = *(const bf16x8*)(Bs[h] + (wcol + 16 * j + frow) * 32 + fsw);
#pragma unroll
            for (int i = 0; i < NI; ++i)
#pragma unroll
                for (int j = 0; j < 4; ++j)
                    acc[i][j] = __builtin_amdgcn_mfma_f32_16x16x32_bf16(
                        afr[i], bfr[j], acc[i][j], 0, 0, 0);
        }
    }

#pragma unroll
    for (int i = 0; i < NI; ++i) {
#pragma unroll
        for (int r = 0; r < 4; ++r) {
            int row = m0 + wrow + i * 16 + (lane >> 4) * 4 + r;
            if (mode <= 1) {
                int t = row & (SEQ - 1);
#pragma unroll
                for (int j = 0; j < 2; ++j) {
                    int dd = j * 16 + (lane & 15);
                    float c = ct[t * 32 + dd];
                    float s = st[t * 32 + dd];
                    float v0 = acc[i][j][r], v1 = acc[i][j + 2][r];
                    float n0v = v0 * c - v1 * s;
                    float n1v = v1 * c + v0 * s;
                    if (mode == 0) { n0v *= 0.125f; n1v *= 0.125f; }
                    acc[i][j][r] = n0v; acc[i][j + 2][r] = n1v;
                }
            }
#pragma unroll
            for (int j = 0; j < 4; ++j) {
                int col = n0 + wcol + j * 16 + (lane & 15);
                float v = acc[i][j][r];
                if (mode == 3)
                    ((float*)Cout)[(size_t)row * N + col] = v + bias[col];
                else
                    ((__bf16*)Cout)[(size_t)row * N + col] = (__bf16)v;
            }
        }
    }
}

// XCD-locality swizzle (verified r7/r8)
template<int GX, int GY>
__device__ __forceinline__ void xcd_swizzle(int& xb, int& yb)
{
    int id = blockIdx.x + GX * blockIdx.y;
    int q  = id & 7;
    int s  = id >> 3;
    xb = s % GX;
    yb = (GY / 8) * q + s / GX;
}

__global__ __launch_bounds__(256) void gemm_out_bf(
    const __bf16* __restrict__ Abf, const __bf16* __restrict__ Wo,
    const float* __restrict__ bias, float* __restrict__ out)
{
    int xb, yb;
    xcd_swizzle<16, 64>(xb, yb);
    gemm_mfma_body<64, 64>(Abf, Wo, out, bias, nullptr, nullptr, 3,
                           DMODEL, DMODEL, yb * 64, xb * 64);
}

// ---------------------------------------------------------------------------
// MFMA sliding-window attention (verified rounds 3-8). One 256-thread block
// per (b, h, 64 q-rows); wave w owns q-rows 16w..16w+15.
// ---------------------------------------------------------------------------
#define QTILE 64
#define KPAD  72    // Ks row (bf16): 36 words/row -> 8 distinct bank offsets
#define VPAD  216   // Vt row: 108 words -> 8 distinct offsets
#define PPAD  168   // Ps row: 84 words -> 8 distinct offsets

__global__ __launch_bounds__(256) void attn_mfma(
    const __bf16* __restrict__ Qb, const __bf16* __restrict__ Kb,
    const __bf16* __restrict__ Vb, __bf16* __restrict__ Abf)
{
    __shared__ __bf16 KsPs[192 * KPAD];  // 27648 B; Ks, then reused as Ps
    __shared__ __bf16 Vt[64 * VPAD];     // 27648 B  (total 55296 B)

    const int tid  = threadIdx.x;
    const int lane = tid & 63;
    const int wv   = tid >> 6;
    const int q0   = blockIdx.x * QTILE;
    const int h    = blockIdx.y;
    const int b    = blockIdx.z;
    const int jbase = q0 - 128;
    const size_t hoff = (size_t)h * HDIM;
    const int nloc  = lane & 15;
    const int mbase = (lane >> 4) * 4;
    const int fk    = (lane >> 4) * 8;

    const __bf16* Kg = Kb + (size_t)(b * SEQ) * DMODEL + hoff;
    const __bf16* Vg = Vb + (size_t)(b * SEQ) * DMODEL + hoff;

    // ---- stage Ks (natural) + Vt (transposed)
#pragma unroll
    for (int it = 0; it < 6; ++it) {
        int idx = tid + it * 256;          // 0..1535
        int jt = idx >> 3;                 // 0..191
        int dq = (idx & 7) * 8;
        int jg = jbase + jt;
        int jc = jg < 0 ? 0 : jg;          // clamp; masked via p=0 later
        bf16x8 kv = *(const bf16x8*)(Kg + (size_t)jc * DMODEL + dq);
        bf16x8 vv = *(const bf16x8*)(Vg + (size_t)jc * DMODEL + dq);
        *(bf16x8*)(KsPs + jt * KPAD + dq) = kv;
#pragma unroll
        for (int e = 0; e < 8; ++e) Vt[(dq + e) * VPAD + jt] = vv[e];
    }
    // zero Vt cols [192,208) (read by PV k-steps; must not be garbage)
#pragma unroll
    for (int it = 0; it < 4; ++it) {
        int idx = tid + it * 256;          // 0..1023
        int d = idx >> 4, c = idx & 15;
        Vt[d * VPAD + 192 + c] = (__bf16)0.0f;
    }
    __syncthreads();

    // ---- Q A-frags direct from global
    const __bf16* Qg = Qb + (size_t)(b * SEQ + q0 + 16 * wv + nloc) * DMODEL + hoff + fk;
    bf16x8 qfr0 = *(const bf16x8*)(Qg);
    bf16x8 qfr1 = *(const bf16x8*)(Qg + 32);

    // ---- S = Q K^T over 9 column tiles
    f32x4 s[9];
#pragma unroll
    for (int c = 0; c < 9; ++c) {
        const __bf16* kp = KsPs + (size_t)(16 * (wv + c) + nloc) * KPAD + fk;
        bf16x8 k0 = *(const bf16x8*)kp;
        bf16x8 k1 = *(const bf16x8*)(kp + 32);
        f32x4 z; z[0] = 0.f; z[1] = 0.f; z[2] = 0.f; z[3] = 0.f;
        z = __builtin_amdgcn_mfma_f32_16x16x32_bf16(qfr0, k0, z, 0, 0, 0);
        z = __builtin_amdgcn_mfma_f32_16x16x32_bf16(qfr1, k1, z, 0, 0, 0);
        s[c] = z;
    }
    __syncthreads();   // all waves done reading Ks; safe to alias with Ps

    // ---- mask + softmax (registers only); write normalized P (bf16)
    float inv_row[4];
#pragma unroll
    for (int r = 0; r < 4; ++r) {
        int rl = 16 * wv + mbase + r;
        float mx = -INFINITY;
#pragma unroll
        for (int c = 0; c < 9; ++c) {
            int jt = 16 * (wv + c) + nloc;
            bool valid = (jt >= rl + 1) && (jt <= rl + 128) && (jbase + jt >= 0);
            float sv = valid ? s[c][r] : -INFINITY;
            s[c][r] = sv;
            mx = fmaxf(mx, sv);
        }
#pragma unroll
        for (int off = 8; off; off >>= 1) mx = fmaxf(mx, __shfl_xor(mx, off));
        float sum = 0.f;
#pragma unroll
        for (int c = 0; c < 9; ++c) {
            float p = __expf(s[c][r] - mx);
            s[c][r] = p;
            sum += p;
        }
#pragma unroll
        for (int off = 8; off; off >>= 1) sum += __shfl_xor(sum, off);
        inv_row[r] = 1.0f / sum;
    }

    __bf16* myP = KsPs + (size_t)wv * 16 * PPAD;
#pragma unroll
    for (int c = 0; c < 9; ++c)
#pragma unroll
        for (int r = 0; r < 4; ++r)
            myP[(mbase + r) * PPAD + 16 * c + nloc] = (__bf16)(s[c][r] * inv_row[r]);
#pragma unroll
    for (int r = 0; r < 4; ++r)       // zero P cols [144,160)
        myP[(mbase + r) * PPAD + 144 + nloc] = (__bf16)0.0f;

    asm volatile("" ::: "memory");
    __builtin_amdgcn_s_waitcnt(0);    // wave-local LDS write->read ordering

    // ---- O = P V  (5 k-steps of 32 keys, 4 d-tiles)
    f32x4 o[4];
#pragma unroll
    for (int j = 0; j < 4; ++j) { o[j][0] = 0.f; o[j][1] = 0.f; o[j][2] = 0.f; o[j][3] = 0.f; }
#pragma unroll
    for (int stp = 0; stp < 5; ++stp) {
        bf16x8 pf = *(const bf16x8*)(myP + nloc * PPAD + 32 * stp + fk);
#pragma unroll
        for (int j = 0; j < 4; ++j) {
            bf16x8 vf = *(const bf16x8*)(Vt + (size_t)(16 * j + nloc) * VPAD
                                         + 16 * wv + 32 * stp + fk);
            o[j] = __builtin_amdgcn_mfma_f32_16x16x32_bf16(pf, vf, o[j], 0, 0, 0);
        }
    }

    // ---- epilogue: C-layout -> global bf16
    __bf16* Og = Abf + (size_t)(b * SEQ + q0 + 16 * wv) * DMODEL + hoff;
#pragma unroll
    for (int j = 0; j < 4; ++j)
#pragma unroll
        for (int r = 0; r < 4; ++r)
            Og[(size_t)(mbase + r) * DMODEL + 16 * j + nloc] = (__bf16)o[j][r];
}

// ---------------------------------------------------------------------------
extern "C" void kernel_launch(void* const* d_in, const int* in_sizes, int n_in,
                              void* d_out, int out_size, void* d_ws, size_t ws_size,
                              hipStream_t stream)
{
    const float* X  = (const float*)d_in[0];
    const float* Wq = (const float*)d_in[1];
    const float* Wk = (const float*)d_in[2];
    const float* Wv = (const float*)d_in[3];
    const float* Wo = (const float*)d_in[4];
    const float* bo = (const float*)d_in[5];
    float* out = (float*)d_out;

    const size_t MB = 1ull << 20;
    __bf16* Xbf = (__bf16*)d_ws;                        // 8 MB; reused as Abf
    __bf16* Wbf = (__bf16*)((char*)d_ws + 8 * MB);      // 8 MB (Wq|Wk|Wv|Wo)
    __bf16* Qb  = (__bf16*)((char*)d_ws + 16 * MB);     // 8 MB
    __bf16* Kb  = (__bf16*)((char*)d_ws + 24 * MB);     // 8 MB
    __bf16* Vb  = (__bf16*)((char*)d_ws + 32 * MB);     // 8 MB
    float*  ctab = (float*)((char*)d_ws + 40 * MB);     // 256 KB
    float*  stab = (float*)((char*)d_ws + 41 * MB);     // 256 KB
    __bf16* Abf = Xbf;   // X dead after QKV projection

    // 1. fp32 -> bf16 conversion + RoPE table (fused)
    {
        int total = (ROWS * DMODEL + 4 * DMODEL * DMODEL) / 4 + SEQ * 32;
        convert_bf16<<<(total + 255) / 256, 256, 0, stream>>>(
            X, Wq, Wk, Wv, Wo, Xbf, Wbf, ctab, stab);
    }
    // 2. Fused QKV projection (N=3072), RoPE (+Q scale); 4-slab ring,
    //    counted vmcnt (T3+T4)
    {
        dim3 grid(12, 16, 1);
        gemm_qkv_ring<<<grid, 512, 0, stream>>>(Xbf, Wbf, Qb, Kb, Vb, ctab, stab);
    }
    // 3. MFMA sliding-window attention -> bf16
    {
        dim3 grid(SEQ / QTILE, NHEADS, BATCH);
        attn_mfma<<<grid, 256, 0, stream>>>(Qb, Kb, Vb, Abf);
    }
    // 4. Output projection + bias (fp32 out); 64x64 tiles (round-0 verified)
    {
        dim3 grid(DMODEL / 64, ROWS / 64, 1);
        gemm_out_bf<<<grid, 256, 0, stream>>>(Abf, Wbf + 3ull * DMODEL * DMODEL, bo, out);
    }
}

// Round 4
// 163.697 us; speedup vs baseline: 1.0324x; 1.0324x over previous
//
#include <hip/hip_runtime.h>

// Problem constants (MultiAttention_61340722921598)
#define BATCH 2
#define SEQ   2048
#define DMODEL 1024
#define NHEADS 16
#define HDIM   64
#define WINDOW 128
#define ROWS  (BATCH * SEQ)          // 4096

typedef __bf16 bf16x8 __attribute__((ext_vector_type(8)));
typedef __bf16 bf16x4 __attribute__((ext_vector_type(4)));
typedef float  f32x4  __attribute__((ext_vector_type(4)));

// async global->LDS, 16B per lane; LDS dest = wave-uniform base + lane*16
__device__ __forceinline__ void async_load16(const __bf16* g, __bf16* l) {
    __builtin_amdgcn_global_load_lds(
        (const __attribute__((address_space(1))) unsigned int*)g,
        (__attribute__((address_space(3))) unsigned int*)l, 16, 0, 0);
}

// ---------------------------------------------------------------------------
// fp32 -> bf16 conversion, 8 floats/thread (2x float4 load, one 16B store —
// G13 sweet spot).  Tail range computes the RoPE cos/sin table (exact libm
// sincosf, matching the fp32 reference).
// ---------------------------------------------------------------------------
__global__ __launch_bounds__(256) void convert_bf16(
    const float* __restrict__ X,
    const float* __restrict__ Wq, const float* __restrict__ Wk,
    const float* __restrict__ Wv, const float* __restrict__ Wo,
    __bf16* __restrict__ Xbf, __bf16* __restrict__ Wbf,
    float* __restrict__ ct, float* __restrict__ st)
{
    const int XN8 = ROWS * DMODEL / 8;     // 524,288 groups of 8
    const int WN8 = DMODEL * DMODEL / 8;   // 131,072 per W (2^17)
    const int TOT = XN8 + 4 * WN8;         // 1,048,576
    int idx = blockIdx.x * blockDim.x + threadIdx.x;

    if (idx < TOT) {
        const float* src;
        __bf16* dst;
        if (idx < XN8) {
            src = X + (size_t)idx * 8;
            dst = Xbf + (size_t)idx * 8;
        } else {
            int rel = idx - XN8;
            int w = rel >> 17;
            int off = rel & (WN8 - 1);
            const float* Wp = (w == 0) ? Wq : (w == 1) ? Wk : (w == 2) ? Wv : Wo;
            src = Wp + (size_t)off * 8;
            dst = Wbf + (size_t)rel * 8;
        }
        float4 a = *(const float4*)src;
        float4 b = *(const float4*)(src + 4);
        bf16x8 o;
        o[0] = (__bf16)a.x; o[1] = (__bf16)a.y; o[2] = (__bf16)a.z; o[3] = (__bf16)a.w;
        o[4] = (__bf16)b.x; o[5] = (__bf16)b.y; o[6] = (__bf16)b.z; o[7] = (__bf16)b.w;
        *(bf16x8*)dst = o;
    } else if (idx < TOT + SEQ * 32) {
        int k = idx - TOT;
        int t = k >> 5, d = k & 31;
        float ang = (float)t * expf(-(float)d * 0.28782313662425572f); // ln(1e4)/32
        float s, c;
        sincosf(ang, &s, &c);
        ct[k] = c; st[k] = s;
    }
}

// ---------------------------------------------------------------------------
// bf16 MFMA GEMM (round-0 measured-best): C[m][n] = sum_k A[m][k] * B[n][k].
// BK=128 (4 x 32-halves, XOR chunk swizzle: LDS row r slot s holds global
// chunk s^((r>>1)&3) via source-address permutation; 0 conflicts measured).
// 256 threads = 4 waves.
//   TN=128 -> 2x2 wave layout: wave = 64x64 outputs, 8 ds_read_b128 per
//             16 MFMA (0.5/MFMA, m97 ratio). LDS 64 KB, 2 blocks/CU.
//   TN=64  -> 4x1 wave layout (used for out-proj).
// Epilogue modes: 0=Q (RoPE+0.125, bf16), 1=K (RoPE, bf16), 2=V (bf16),
// 3=fp32+bias. wcol is a multiple of 64 in both layouts -> RoPE pairs
// (d, d+32) stay in one wave as (acc[i][j], acc[i][j+2]), d=j*16+(lane&15).
// A/B-frag: elem[row=lane&15][k=(lane>>4)*8+j]; C/D: col=lane&15,
// row=(lane>>4)*4+reg (verified m89, rounds 2-8).
// ---------------------------------------------------------------------------
template<int TM, int TN>
__device__ __forceinline__ void gemm_mfma_body(
    const __bf16* __restrict__ A, const __bf16* __restrict__ B,
    void* __restrict__ Cout, const float* __restrict__ bias,
    const float* __restrict__ ct, const float* __restrict__ st,
    int mode, int N, int K, int m0, int n0)
{
    constexpr bool SQ = (TN == 128);          // 2x2 wave layout
    constexpr int NI = SQ ? 4 : (TM / 64);    // 16-row i-tiles per wave
    constexpr int NAC = TM / 64;              // A staging calls per wave/half
    constexpr int NBC = TN / 64;              // B staging calls per wave/half
    __shared__ __bf16 As[4][TM * 32];
    __shared__ __bf16 Bs[4][TN * 32];

    const int tid  = threadIdx.x;
    const int lane = tid & 63;
    const int wv   = tid >> 6;
    const int wrow = SQ ? (wv >> 1) * 64 : wv * (TM / 4);
    const int wcol = SQ ? (wv & 1) * 64 : 0;

    // staging map (per 16-row call): lane -> row lane>>2, slot lane&3,
    // source chunk (lane&3)^((lane>>3)&3); row-base-invariant (base % 16 == 0)
    const int srow = lane >> 2;
    const int schk = (lane & 3) ^ ((lane >> 3) & 3);
    const int arbase = wv * (TM / 4);
    const int brbase = wv * (TN / 4);

    const __bf16* gA0 = A + (size_t)(m0 + arbase + srow) * K + 8 * schk;
    const __bf16* gA1 = gA0 + (size_t)16 * K;
    const __bf16* gB0 = B + (size_t)(n0 + brbase + srow) * K + 8 * schk;
    const __bf16* gB1 = gB0 + (size_t)16 * K;

    // fragment read map: row frow, global chunk lane>>4 at swizzled slot
    const int frow = lane & 15;
    const int fsw  = 8 * ((lane >> 4) ^ ((frow >> 1) & 3));

    f32x4 acc[NI][4];
#pragma unroll
    for (int i = 0; i < NI; ++i)
#pragma unroll
        for (int j = 0; j < 4; ++j) {
            acc[i][j][0] = 0.f; acc[i][j][1] = 0.f;
            acc[i][j][2] = 0.f; acc[i][j][3] = 0.f;
        }

    for (int k0 = 0; k0 < K; k0 += 128) {
        __syncthreads();                 // prior iter's LDS reads complete
#pragma unroll
        for (int h = 0; h < 4; ++h) {
            async_load16(gA0 + k0 + 32 * h, As[h] + arbase * 32);
            if (NAC == 2)
                async_load16(gA1 + k0 + 32 * h, As[h] + (arbase + 16) * 32);
            async_load16(gB0 + k0 + 32 * h, Bs[h] + brbase * 32);
            if (NBC == 2)
                async_load16(gB1 + k0 + 32 * h, Bs[h] + (brbase + 16) * 32);
        }
        __syncthreads();                 // drains vmcnt: staging visible

#pragma unroll
        for (int h = 0; h < 4; ++h) {
            bf16x8 afr[NI], bfr[4];
#pragma unroll
            for (int i = 0; i < NI; ++i)
                afr[i] = *(const bf16x8*)(As[h] + (wrow + 16 * i + frow) * 32 + fsw);
#pragma unroll
            for (int j = 0; j < 4; ++j)
                bfr[j] = *(const bf16x8*)(Bs[h] + (wcol + 16 * j + frow) * 32 + fsw);
#pragma unroll
            for (int i = 0; i < NI; ++i)
#pragma unroll
                for (int j = 0; j < 4; ++j)
                    acc[i][j] = __builtin_amdgcn_mfma_f32_16x16x32_bf16(
                        afr[i], bfr[j], acc[i][j], 0, 0, 0);
        }
    }

#pragma unroll
    for (int i = 0; i < NI; ++i) {
#pragma unroll
        for (int r = 0; r < 4; ++r) {
            int row = m0 + wrow + i * 16 + (lane >> 4) * 4 + r;
            if (mode <= 1) {
                // RoPE: pairs (d, d+32) in (acc[i][j], acc[i][j+2]), d=j*16+(lane&15)<32
                int t = row & (SEQ - 1);
#pragma unroll
                for (int j = 0; j < 2; ++j) {
                    int dd = j * 16 + (lane & 15);
                    float c = ct[t * 32 + dd];
                    float s = st[t * 32 + dd];
                    float v0 = acc[i][j][r], v1 = acc[i][j + 2][r];
                    float n0v = v0 * c - v1 * s;
                    float n1v = v1 * c + v0 * s;
                    if (mode == 0) { n0v *= 0.125f; n1v *= 0.125f; }
                    acc[i][j][r] = n0v; acc[i][j + 2][r] = n1v;
                }
            }
#pragma unroll
            for (int j = 0; j < 4; ++j) {
                int col = n0 + wcol + j * 16 + (lane & 15);
                float v = acc[i][j][r];
                if (mode == 3)
                    ((float*)Cout)[(size_t)row * N + col] = v + bias[col];
                else
                    ((__bf16*)Cout)[(size_t)row * N + col] = (__bf16)v;
            }
        }
    }
}

// XCD-locality swizzle (verified r7/r8): id = bx + GX*by, XCD = id&7
// (round-robin dispatch). Each XCD gets GY/8 y-stripes so the GX blocks
// sharing one A-row-tile sit on ONE XCD; z-stride GX*GY % 8 == 0 keeps the
// same (x,y) on the same XCD across z.
template<int GX, int GY>
__device__ __forceinline__ void xcd_swizzle(int& xb, int& yb)
{
    int id = blockIdx.x + GX * blockIdx.y;
    int q  = id & 7;
    int s  = id >> 3;
    xb = s % GX;
    yb = (GY / 8) * q + s / GX;
}

__global__ __launch_bounds__(256) void gemm_qkv_bf(
    const __bf16* __restrict__ X, const __bf16* __restrict__ Wbf,
    __bf16* __restrict__ Qb, __bf16* __restrict__ Kb, __bf16* __restrict__ Vb,
    const float* __restrict__ ct, const float* __restrict__ st)
{
    const int z = blockIdx.z;
    const __bf16* W = Wbf + (size_t)z * (DMODEL * DMODEL);
    __bf16* C = (z == 0) ? Qb : (z == 1) ? Kb : Vb;
    int xb, yb;
    xcd_swizzle<8, 32>(xb, yb);
    gemm_mfma_body<128, 128>(X, W, C, nullptr, ct, st, z, DMODEL, DMODEL,
                             yb * 128, xb * 128);
}

__global__ __launch_bounds__(256) void gemm_out_bf(
    const __bf16* __restrict__ Abf, const __bf16* __restrict__ Wo,
    const float* __restrict__ bias, float* __restrict__ out)
{
    int xb, yb;
    xcd_swizzle<16, 64>(xb, yb);
    gemm_mfma_body<64, 64>(Abf, Wo, out, bias, nullptr, nullptr, 3,
                           DMODEL, DMODEL, yb * 64, xb * 64);
}

// ---------------------------------------------------------------------------
// MFMA sliding-window attention (verified rounds 3-8 + this round's staging
// split).  One 256-thread block per (b, h, 64 q-rows); wave w owns q-rows
// 16w..16w+15.  Round-4 changes (T14 pattern): (1) Q fragment loads hoisted
// to the very top (independent of staging; latency hides under it);
// (2) staging split into issue-all-12-global-loads -> write-all-LDS, so the
// 6 global-load latencies overlap instead of serializing with dependent
// LDS writes.
// ---------------------------------------------------------------------------
#define QTILE 64
#define KPAD  72    // Ks row (bf16): 36 words/row -> 8 distinct bank offsets
#define VPAD  216   // Vt row: 108 words -> 8 distinct offsets
#define PPAD  168   // Ps row: 84 words -> 8 distinct offsets

__global__ __launch_bounds__(256) void attn_mfma(
    const __bf16* __restrict__ Qb, const __bf16* __restrict__ Kb,
    const __bf16* __restrict__ Vb, __bf16* __restrict__ Abf)
{
    __shared__ __bf16 KsPs[192 * KPAD];  // 27648 B; Ks, then reused as Ps
    __shared__ __bf16 Vt[64 * VPAD];     // 27648 B  (total 55296 B)

    const int tid  = threadIdx.x;
    const int lane = tid & 63;
    const int wv   = tid >> 6;
    const int q0   = blockIdx.x * QTILE;
    const int h    = blockIdx.y;
    const int b    = blockIdx.z;
    const int jbase = q0 - 128;
    const size_t hoff = (size_t)h * HDIM;
    const int nloc  = lane & 15;
    const int mbase = (lane >> 4) * 4;
    const int fk    = (lane >> 4) * 8;

    const __bf16* Kg = Kb + (size_t)(b * SEQ) * DMODEL + hoff;
    const __bf16* Vg = Vb + (size_t)(b * SEQ) * DMODEL + hoff;

    // ---- Q A-frags direct from global, hoisted (independent of staging)
    const __bf16* Qg = Qb + (size_t)(b * SEQ + q0 + 16 * wv + nloc) * DMODEL + hoff + fk;
    bf16x8 qfr0 = *(const bf16x8*)(Qg);
    bf16x8 qfr1 = *(const bf16x8*)(Qg + 32);

    // ---- stage Ks (natural) + Vt (transposed): issue all loads, then write
    bf16x8 kvv[6], vvv[6];
#pragma unroll
    for (int it = 0; it < 6; ++it) {
        int idx = tid + it * 256;          // 0..1535
        int jt = idx >> 3;                 // 0..191
        int dq = (idx & 7) * 8;
        int jg = jbase + jt;
        int jc = jg < 0 ? 0 : jg;          // clamp; masked via p=0 later
        kvv[it] = *(const bf16x8*)(Kg + (size_t)jc * DMODEL + dq);
        vvv[it] = *(const bf16x8*)(Vg + (size_t)jc * DMODEL + dq);
    }
#pragma unroll
    for (int it = 0; it < 6; ++it) {
        int idx = tid + it * 256;
        int jt = idx >> 3;
        int dq = (idx & 7) * 8;
        *(bf16x8*)(KsPs + jt * KPAD + dq) = kvv[it];
#pragma unroll
        for (int e = 0; e < 8; ++e) Vt[(dq + e) * VPAD + jt] = vvv[it][e];
    }
    // zero Vt cols [192,208) (read by PV k-steps; must not be garbage)
#pragma unroll
    for (int it = 0; it < 4; ++it) {
        int idx = tid + it * 256;          // 0..1023
        int d = idx >> 4, c = idx & 15;
        Vt[d * VPAD + 192 + c] = (__bf16)0.0f;
    }
    __syncthreads();

    // ---- S = Q K^T over 9 column tiles
    f32x4 s[9];
#pragma unroll
    for (int c = 0; c < 9; ++c) {
        const __bf16* kp = KsPs + (size_t)(16 * (wv + c) + nloc) * KPAD + fk;
        bf16x8 k0 = *(const bf16x8*)kp;
        bf16x8 k1 = *(const bf16x8*)(kp + 32);
        f32x4 z; z[0] = 0.f; z[1] = 0.f; z[2] = 0.f; z[3] = 0.f;
        z = __builtin_amdgcn_mfma_f32_16x16x32_bf16(qfr0, k0, z, 0, 0, 0);
        z = __builtin_amdgcn_mfma_f32_16x16x32_bf16(qfr1, k1, z, 0, 0, 0);
        s[c] = z;
    }
    __syncthreads();   // all waves done reading Ks; safe to alias with Ps

    // ---- mask + softmax (registers only); write normalized P (bf16)
    float inv_row[4];
#pragma unroll
    for (int r = 0; r < 4; ++r) {
        int rl = 16 * wv + mbase + r;
        float mx = -INFINITY;
#pragma unroll
        for (int c = 0; c < 9; ++c) {
            int jt = 16 * (wv + c) + nloc;
            bool valid = (jt >= rl + 1) && (jt <= rl + 128) && (jbase + jt >= 0);
            float sv = valid ? s[c][r] : -INFINITY;
            s[c][r] = sv;
            mx = fmaxf(mx, sv);
        }
#pragma unroll
        for (int off = 8; off; off >>= 1) mx = fmaxf(mx, __shfl_xor(mx, off));
        float sum = 0.f;
#pragma unroll
        for (int c = 0; c < 9; ++c) {
            float p = __expf(s[c][r] - mx);
            s[c][r] = p;
            sum += p;
        }
#pragma unroll
        for (int off = 8; off; off >>= 1) sum += __shfl_xor(sum, off);
        inv_row[r] = 1.0f / sum;
    }

    __bf16* myP = KsPs + (size_t)wv * 16 * PPAD;
#pragma unroll
    for (int c = 0; c < 9; ++c)
#pragma unroll
        for (int r = 0; r < 4; ++r)
            myP[(mbase + r) * PPAD + 16 * c + nloc] = (__bf16)(s[c][r] * inv_row[r]);
#pragma unroll
    for (int r = 0; r < 4; ++r)       // zero P cols [144,160)
        myP[(mbase + r) * PPAD + 144 + nloc] = (__bf16)0.0f;

    asm volatile("" ::: "memory");
    __builtin_amdgcn_s_waitcnt(0);    // wave-local LDS write->read ordering

    // ---- O = P V  (5 k-steps of 32 keys, 4 d-tiles)
    f32x4 o[4];
#pragma unroll
    for (int j = 0; j < 4; ++j) { o[j][0] = 0.f; o[j][1] = 0.f; o[j][2] = 0.f; o[j][3] = 0.f; }
#pragma unroll
    for (int stp = 0; stp < 5; ++stp) {
        bf16x8 pf = *(const bf16x8*)(myP + nloc * PPAD + 32 * stp + fk);
#pragma unroll
        for (int j = 0; j < 4; ++j) {
            bf16x8 vf = *(const bf16x8*)(Vt + (size_t)(16 * j + nloc) * VPAD
                                         + 16 * wv + 32 * stp + fk);
            o[j] = __builtin_amdgcn_mfma_f32_16x16x32_bf16(pf, vf, o[j], 0, 0, 0);
        }
    }

    // ---- epilogue: C-layout -> global bf16
    __bf16* Og = Abf + (size_t)(b * SEQ + q0 + 16 * wv) * DMODEL + hoff;
#pragma unroll
    for (int j = 0; j < 4; ++j)
#pragma unroll
        for (int r = 0; r < 4; ++r)
            Og[(size_t)(mbase + r) * DMODEL + 16 * j + nloc] = (__bf16)o[j][r];
}

// ---------------------------------------------------------------------------
extern "C" void kernel_launch(void* const* d_in, const int* in_sizes, int n_in,
                              void* d_out, int out_size, void* d_ws, size_t ws_size,
                              hipStream_t stream)
{
    const float* X  = (const float*)d_in[0];
    const float* Wq = (const float*)d_in[1];
    const float* Wk = (const float*)d_in[2];
    const float* Wv = (const float*)d_in[3];
    const float* Wo = (const float*)d_in[4];
    const float* bo = (const float*)d_in[5];
    float* out = (float*)d_out;

    const size_t MB = 1ull << 20;
    __bf16* Xbf = (__bf16*)d_ws;                        // 8 MB; reused as Abf
    __bf16* Wbf = (__bf16*)((char*)d_ws + 8 * MB);      // 8 MB (Wq|Wk|Wv|Wo)
    __bf16* Qb  = (__bf16*)((char*)d_ws + 16 * MB);     // 8 MB
    __bf16* Kb  = (__bf16*)((char*)d_ws + 24 * MB);     // 8 MB
    __bf16* Vb  = (__bf16*)((char*)d_ws + 32 * MB);     // 8 MB
    float*  ctab = (float*)((char*)d_ws + 40 * MB);     // 256 KB
    float*  stab = (float*)((char*)d_ws + 41 * MB);     // 256 KB
    __bf16* Abf = Xbf;   // X dead after QKV projection

    // 1. fp32 -> bf16 conversion + RoPE table (fused); 8 floats/thread
    {
        int total = (ROWS * DMODEL + 4 * DMODEL * DMODEL) / 8 + SEQ * 32;
        convert_bf16<<<(total + 255) / 256, 256, 0, stream>>>(
            X, Wq, Wk, Wv, Wo, Xbf, Wbf, ctab, stab);
    }
    // 2. QKV projections with fused RoPE (+Q scale), bf16 out; 128x128 tiles
    //    (round-0 measured-best config)
    {
        dim3 grid(DMODEL / 128, ROWS / 128, 3);
        gemm_qkv_bf<<<grid, 256, 0, stream>>>(Xbf, Wbf, Qb, Kb, Vb, ctab, stab);
    }
    // 3. MFMA sliding-window attention -> bf16 (staging split + Q hoist)
    {
        dim3 grid(SEQ / QTILE, NHEADS, BATCH);
        attn_mfma<<<grid, 256, 0, stream>>>(Qb, Kb, Vb, Abf);
    }
    // 4. Output projection + bias (fp32 out); 64x64 tiles (round-0 verified)
    {
        dim3 grid(DMODEL / 64, ROWS / 64, 1);
        gemm_out_bf<<<grid, 256, 0, stream>>>(Abf, Wbf + 3ull * DMODEL * DMODEL, bo, out);
    }
}

// Round 5
// 163.052 us; speedup vs baseline: 1.0365x; 1.0040x over previous
//
#include <hip/hip_runtime.h>

// Problem constants (MultiAttention_61340722921598)
#define BATCH 2
#define SEQ   2048
#define DMODEL 1024
#define NHEADS 16
#define HDIM   64
#define WINDOW 128
#define ROWS  (BATCH * SEQ)          // 4096

typedef __bf16 bf16x8 __attribute__((ext_vector_type(8)));
typedef __bf16 bf16x4 __attribute__((ext_vector_type(4)));
typedef float  f32x4  __attribute__((ext_vector_type(4)));

// async global->LDS, 16B per lane; LDS dest = wave-uniform base + lane*16
__device__ __forceinline__ void async_load16(const __bf16* g, __bf16* l) {
    __builtin_amdgcn_global_load_lds(
        (const __attribute__((address_space(1))) unsigned int*)g,
        (__attribute__((address_space(3))) unsigned int*)l, 16, 0, 0);
}

// ---------------------------------------------------------------------------
// fp32 -> bf16 conversion, 8 floats/thread (2x float4 load, one 16B store —
// G13 sweet spot).  Tail range computes the RoPE cos/sin table (exact libm
// sincosf, matching the fp32 reference).
// ---------------------------------------------------------------------------
__global__ __launch_bounds__(256) void convert_bf16(
    const float* __restrict__ X,
    const float* __restrict__ Wq, const float* __restrict__ Wk,
    const float* __restrict__ Wv, const float* __restrict__ Wo,
    __bf16* __restrict__ Xbf, __bf16* __restrict__ Wbf,
    float* __restrict__ ct, float* __restrict__ st)
{
    const int XN8 = ROWS * DMODEL / 8;     // 524,288 groups of 8
    const int WN8 = DMODEL * DMODEL / 8;   // 131,072 per W (2^17)
    const int TOT = XN8 + 4 * WN8;         // 1,048,576
    int idx = blockIdx.x * blockDim.x + threadIdx.x;

    if (idx < TOT) {
        const float* src;
        __bf16* dst;
        if (idx < XN8) {
            src = X + (size_t)idx * 8;
            dst = Xbf + (size_t)idx * 8;
        } else {
            int rel = idx - XN8;
            int w = rel >> 17;
            int off = rel & (WN8 - 1);
            const float* Wp = (w == 0) ? Wq : (w == 1) ? Wk : (w == 2) ? Wv : Wo;
            src = Wp + (size_t)off * 8;
            dst = Wbf + (size_t)rel * 8;
        }
        float4 a = *(const float4*)src;
        float4 b = *(const float4*)(src + 4);
        bf16x8 o;
        o[0] = (__bf16)a.x; o[1] = (__bf16)a.y; o[2] = (__bf16)a.z; o[3] = (__bf16)a.w;
        o[4] = (__bf16)b.x; o[5] = (__bf16)b.y; o[6] = (__bf16)b.z; o[7] = (__bf16)b.w;
        *(bf16x8*)dst = o;
    } else if (idx < TOT + SEQ * 32) {
        int k = idx - TOT;
        int t = k >> 5, d = k & 31;
        float ang = (float)t * expf(-(float)d * 0.28782313662425572f); // ln(1e4)/32
        float s, c;
        sincosf(ang, &s, &c);
        ct[k] = c; st[k] = s;
    }
}

// ---------------------------------------------------------------------------
// bf16 MFMA GEMM (round-0 measured-best): C[m][n] = sum_k A[m][k] * B[n][k].
// BK=128 (4 x 32-halves, XOR chunk swizzle: LDS row r slot s holds global
// chunk s^((r>>1)&3) via source-address permutation; 0 conflicts measured).
// 256 threads = 4 waves.
//   TN=128 -> 2x2 wave layout: wave = 64x64 outputs, 8 ds_read_b128 per
//             16 MFMA (0.5/MFMA, m97 ratio). LDS 64 KB, 2 blocks/CU.
//   TN=64  -> 4x1 wave layout (used for out-proj).
// Epilogue modes: 0=Q (RoPE+0.125, bf16), 1=K (RoPE, bf16), 2=V (bf16),
// 3=fp32+bias. wcol is a multiple of 64 in both layouts -> RoPE pairs
// (d, d+32) stay in one wave as (acc[i][j], acc[i][j+2]), d=j*16+(lane&15).
// A/B-frag: elem[row=lane&15][k=(lane>>4)*8+j]; C/D: col=lane&15,
// row=(lane>>4)*4+reg (verified m89, rounds 2-8).
// ---------------------------------------------------------------------------
template<int TM, int TN>
__device__ __forceinline__ void gemm_mfma_body(
    const __bf16* __restrict__ A, const __bf16* __restrict__ B,
    void* __restrict__ Cout, const float* __restrict__ bias,
    const float* __restrict__ ct, const float* __restrict__ st,
    int mode, int N, int K, int m0, int n0)
{
    constexpr bool SQ = (TN == 128);          // 2x2 wave layout
    constexpr int NI = SQ ? 4 : (TM / 64);    // 16-row i-tiles per wave
    constexpr int NAC = TM / 64;              // A staging calls per wave/half
    constexpr int NBC = TN / 64;              // B staging calls per wave/half
    __shared__ __bf16 As[4][TM * 32];
    __shared__ __bf16 Bs[4][TN * 32];

    const int tid  = threadIdx.x;
    const int lane = tid & 63;
    const int wv   = tid >> 6;
    const int wrow = SQ ? (wv >> 1) * 64 : wv * (TM / 4);
    const int wcol = SQ ? (wv & 1) * 64 : 0;

    // staging map (per 16-row call): lane -> row lane>>2, slot lane&3,
    // source chunk (lane&3)^((lane>>3)&3); row-base-invariant (base % 16 == 0)
    const int srow = lane >> 2;
    const int schk = (lane & 3) ^ ((lane >> 3) & 3);
    const int arbase = wv * (TM / 4);
    const int brbase = wv * (TN / 4);

    const __bf16* gA0 = A + (size_t)(m0 + arbase + srow) * K + 8 * schk;
    const __bf16* gA1 = gA0 + (size_t)16 * K;
    const __bf16* gB0 = B + (size_t)(n0 + brbase + srow) * K + 8 * schk;
    const __bf16* gB1 = gB0 + (size_t)16 * K;

    // fragment read map: row frow, global chunk lane>>4 at swizzled slot
    const int frow = lane & 15;
    const int fsw  = 8 * ((lane >> 4) ^ ((frow >> 1) & 3));

    f32x4 acc[NI][4];
#pragma unroll
    for (int i = 0; i < NI; ++i)
#pragma unroll
        for (int j = 0; j < 4; ++j) {
            acc[i][j][0] = 0.f; acc[i][j][1] = 0.f;
            acc[i][j][2] = 0.f; acc[i][j][3] = 0.f;
        }

    for (int k0 = 0; k0 < K; k0 += 128) {
        __syncthreads();                 // prior iter's LDS reads complete
#pragma unroll
        for (int h = 0; h < 4; ++h) {
            async_load16(gA0 + k0 + 32 * h, As[h] + arbase * 32);
            if (NAC == 2)
                async_load16(gA1 + k0 + 32 * h, As[h] + (arbase + 16) * 32);
            async_load16(gB0 + k0 + 32 * h, Bs[h] + brbase * 32);
            if (NBC == 2)
                async_load16(gB1 + k0 + 32 * h, Bs[h] + (brbase + 16) * 32);
        }
        __syncthreads();                 // drains vmcnt: staging visible

#pragma unroll
        for (int h = 0; h < 4; ++h) {
            bf16x8 afr[NI], bfr[4];
#pragma unroll
            for (int i = 0; i < NI; ++i)
                afr[i] = *(const bf16x8*)(As[h] + (wrow + 16 * i + frow) * 32 + fsw);
#pragma unroll
            for (int j = 0; j < 4; ++j)
                bfr[j] = *(const bf16x8*)(Bs[h] + (wcol + 16 * j + frow) * 32 + fsw);
#pragma unroll
            for (int i = 0; i < NI; ++i)
#pragma unroll
                for (int j = 0; j < 4; ++j)
                    acc[i][j] = __builtin_amdgcn_mfma_f32_16x16x32_bf16(
                        afr[i], bfr[j], acc[i][j], 0, 0, 0);
        }
    }

#pragma unroll
    for (int i = 0; i < NI; ++i) {
#pragma unroll
        for (int r = 0; r < 4; ++r) {
            int row = m0 + wrow + i * 16 + (lane >> 4) * 4 + r;
            if (mode <= 1) {
                // RoPE: pairs (d, d+32) in (acc[i][j], acc[i][j+2]), d=j*16+(lane&15)<32
                int t = row & (SEQ - 1);
#pragma unroll
                for (int j = 0; j < 2; ++j) {
                    int dd = j * 16 + (lane & 15);
                    float c = ct[t * 32 + dd];
                    float s = st[t * 32 + dd];
                    float v0 = acc[i][j][r], v1 = acc[i][j + 2][r];
                    float n0v = v0 * c - v1 * s;
                    float n1v = v1 * c + v0 * s;
                    if (mode == 0) { n0v *= 0.125f; n1v *= 0.125f; }
                    acc[i][j][r] = n0v; acc[i][j + 2][r] = n1v;
                }
            }
#pragma unroll
            for (int j = 0; j < 4; ++j) {
                int col = n0 + wcol + j * 16 + (lane & 15);
                float v = acc[i][j][r];
                if (mode == 3)
                    ((float*)Cout)[(size_t)row * N + col] = v + bias[col];
                else
                    ((__bf16*)Cout)[(size_t)row * N + col] = (__bf16)v;
            }
        }
    }
}

// XCD-locality swizzle (verified r7/r8): id = bx + GX*by, XCD = id&7
// (round-robin dispatch). Each XCD gets GY/8 y-stripes so the GX blocks
// sharing one A-row-tile sit on ONE XCD; z-stride GX*GY % 8 == 0 keeps the
// same (x,y) on the same XCD across z.
template<int GX, int GY>
__device__ __forceinline__ void xcd_swizzle(int& xb, int& yb)
{
    int id = blockIdx.x + GX * blockIdx.y;
    int q  = id & 7;
    int s  = id >> 3;
    xb = s % GX;
    yb = (GY / 8) * q + s / GX;
}

__global__ __launch_bounds__(256) void gemm_qkv_bf(
    const __bf16* __restrict__ X, const __bf16* __restrict__ Wbf,
    __bf16* __restrict__ Qb, __bf16* __restrict__ Kb, __bf16* __restrict__ Vb,
    const float* __restrict__ ct, const float* __restrict__ st)
{
    const int z = blockIdx.z;
    const __bf16* W = Wbf + (size_t)z * (DMODEL * DMODEL);
    __bf16* C = (z == 0) ? Qb : (z == 1) ? Kb : Vb;
    int xb, yb;
    xcd_swizzle<8, 32>(xb, yb);
    gemm_mfma_body<128, 128>(X, W, C, nullptr, ct, st, z, DMODEL, DMODEL,
                             yb * 128, xb * 128);
}

__global__ __launch_bounds__(256) void gemm_out_bf(
    const __bf16* __restrict__ Abf, const __bf16* __restrict__ Wo,
    const float* __restrict__ bias, float* __restrict__ out)
{
    int xb, yb;
    xcd_swizzle<16, 64>(xb, yb);
    gemm_mfma_body<64, 64>(Abf, Wo, out, bias, nullptr, nullptr, 3,
                           DMODEL, DMODEL, yb * 64, xb * 64);
}

// ---------------------------------------------------------------------------
// MFMA sliding-window attention.  One 256-thread block per (b, h, 64 q-rows);
// wave w owns q-rows 16w..16w+15.
// Round-5 changes:
//  * VPAD 216 -> 200 (same 2-way bank pattern: stride-words mod 32 = 4),
//    zero-pad columns [192,208) removed; the only reads that touched them
//    (wv=3, stp=4, hi>=2) are clamped to col 0 — their P multipliers
//    (cols 144..159) are zeroed, and stored V values are finite, so the
//    product is exactly 0 as before.
//  * LDS 55296 -> 53248 B => 3 blocks/CU (was 2); __launch_bounds__(256,3).
//  * T5 setprio around QK and PV MFMA clusters (m191 regime: independent
//    blocks per CU at different phases).
// ---------------------------------------------------------------------------
#define QTILE 64
#define KPAD  72    // Ks row (bf16): 36 words/row -> 8 distinct bank offsets
#define VPAD  200   // Vt row: 100 words -> 8 distinct bank offsets (2-way)
#define PPAD  168   // Ps row: 84 words -> 8 distinct offsets

__global__ __launch_bounds__(256, 3) void attn_mfma(
    const __bf16* __restrict__ Qb, const __bf16* __restrict__ Kb,
    const __bf16* __restrict__ Vb, __bf16* __restrict__ Abf)
{
    __shared__ __bf16 KsPs[192 * KPAD];  // 27648 B; Ks, then reused as Ps
    __shared__ __bf16 Vt[64 * VPAD];     // 25600 B  (total 53248 B -> 3/CU)

    const int tid  = threadIdx.x;
    const int lane = tid & 63;
    const int wv   = tid >> 6;
    const int q0   = blockIdx.x * QTILE;
    const int h    = blockIdx.y;
    const int b    = blockIdx.z;
    const int jbase = q0 - 128;
    const size_t hoff = (size_t)h * HDIM;
    const int nloc  = lane & 15;
    const int mbase = (lane >> 4) * 4;
    const int fk    = (lane >> 4) * 8;

    const __bf16* Kg = Kb + (size_t)(b * SEQ) * DMODEL + hoff;
    const __bf16* Vg = Vb + (size_t)(b * SEQ) * DMODEL + hoff;

    // ---- stage Ks (natural) + Vt (transposed)
#pragma unroll
    for (int it = 0; it < 6; ++it) {
        int idx = tid + it * 256;          // 0..1535
        int jt = idx >> 3;                 // 0..191
        int dq = (idx & 7) * 8;
        int jg = jbase + jt;
        int jc = jg < 0 ? 0 : jg;          // clamp; masked via p=0 later
        bf16x8 kv = *(const bf16x8*)(Kg + (size_t)jc * DMODEL + dq);
        bf16x8 vv = *(const bf16x8*)(Vg + (size_t)jc * DMODEL + dq);
        *(bf16x8*)(KsPs + jt * KPAD + dq) = kv;
#pragma unroll
        for (int e = 0; e < 8; ++e) Vt[(dq + e) * VPAD + jt] = vv[e];
    }
    __syncthreads();

    // ---- Q A-frags direct from global
    const __bf16* Qg = Qb + (size_t)(b * SEQ + q0 + 16 * wv + nloc) * DMODEL + hoff + fk;
    bf16x8 qfr0 = *(const bf16x8*)(Qg);
    bf16x8 qfr1 = *(const bf16x8*)(Qg + 32);

    // ---- S = Q K^T over 9 column tiles
    f32x4 s[9];
    __builtin_amdgcn_s_setprio(1);
#pragma unroll
    for (int c = 0; c < 9; ++c) {
        const __bf16* kp = KsPs + (size_t)(16 * (wv + c) + nloc) * KPAD + fk;
        bf16x8 k0 = *(const bf16x8*)kp;
        bf16x8 k1 = *(const bf16x8*)(kp + 32);
        f32x4 z; z[0] = 0.f; z[1] = 0.f; z[2] = 0.f; z[3] = 0.f;
        z = __builtin_amdgcn_mfma_f32_16x16x32_bf16(qfr0, k0, z, 0, 0, 0);
        z = __builtin_amdgcn_mfma_f32_16x16x32_bf16(qfr1, k1, z, 0, 0, 0);
        s[c] = z;
    }
    __builtin_amdgcn_s_setprio(0);
    __syncthreads();   // all waves done reading Ks; safe to alias with Ps

    // ---- mask + softmax (registers only); write normalized P (bf16)
    float inv_row[4];
#pragma unroll
    for (int r = 0; r < 4; ++r) {
        int rl = 16 * wv + mbase + r;
        float mx = -INFINITY;
#pragma unroll
        for (int c = 0; c < 9; ++c) {
            int jt = 16 * (wv + c) + nloc;
            bool valid = (jt >= rl + 1) && (jt <= rl + 128) && (jbase + jt >= 0);
            float sv = valid ? s[c][r] : -INFINITY;
            s[c][r] = sv;
            mx = fmaxf(mx, sv);
        }
#pragma unroll
        for (int off = 8; off; off >>= 1) mx = fmaxf(mx, __shfl_xor(mx, off));
        float sum = 0.f;
#pragma unroll
        for (int c = 0; c < 9; ++c) {
            float p = __expf(s[c][r] - mx);
            s[c][r] = p;
            sum += p;
        }
#pragma unroll
        for (int off = 8; off; off >>= 1) sum += __shfl_xor(sum, off);
        inv_row[r] = 1.0f / sum;
    }

    __bf16* myP = KsPs + (size_t)wv * 16 * PPAD;
#pragma unroll
    for (int c = 0; c < 9; ++c)
#pragma unroll
        for (int r = 0; r < 4; ++r)
            myP[(mbase + r) * PPAD + 16 * c + nloc] = (__bf16)(s[c][r] * inv_row[r]);
#pragma unroll
    for (int r = 0; r < 4; ++r)       // zero P cols [144,160)
        myP[(mbase + r) * PPAD + 144 + nloc] = (__bf16)0.0f;

    asm volatile("" ::: "memory");
    __builtin_amdgcn_s_waitcnt(0);    // wave-local LDS write->read ordering

    // ---- O = P V  (5 k-steps of 32 keys, 4 d-tiles)
    f32x4 o[4];
#pragma unroll
    for (int j = 0; j < 4; ++j) { o[j][0] = 0.f; o[j][1] = 0.f; o[j][2] = 0.f; o[j][3] = 0.f; }
    __builtin_amdgcn_s_setprio(1);
#pragma unroll
    for (int stp = 0; stp < 5; ++stp) {
        bf16x8 pf = *(const bf16x8*)(myP + nloc * PPAD + 32 * stp + fk);
        int vcol = 16 * wv + 32 * stp + fk;
        if (vcol >= 192) vcol = 0;        // P cols 144..159 are zero; stay in-bounds
#pragma unroll
        for (int j = 0; j < 4; ++j) {
            bf16x8 vf = *(const bf16x8*)(Vt + (size_t)(16 * j + nloc) * VPAD + vcol);
            o[j] = __builtin_amdgcn_mfma_f32_16x16x32_bf16(pf, vf, o[j], 0, 0, 0);
        }
    }
    __builtin_amdgcn_s_setprio(0);

    // ---- epilogue: C-layout -> global bf16
    __bf16* Og = Abf + (size_t)(b * SEQ + q0 + 16 * wv) * DMODEL + hoff;
#pragma unroll
    for (int j = 0; j < 4; ++j)
#pragma unroll
        for (int r = 0; r < 4; ++r)
            Og[(size_t)(mbase + r) * DMODEL + 16 * j + nloc] = (__bf16)o[j][r];
}

// ---------------------------------------------------------------------------
extern "C" void kernel_launch(void* const* d_in, const int* in_sizes, int n_in,
                              void* d_out, int out_size, void* d_ws, size_t ws_size,
                              hipStream_t stream)
{
    const float* X  = (const float*)d_in[0];
    const float* Wq = (const float*)d_in[1];
    const float* Wk = (const float*)d_in[2];
    const float* Wv = (const float*)d_in[3];
    const float* Wo = (const float*)d_in[4];
    const float* bo = (const float*)d_in[5];
    float* out = (float*)d_out;

    const size_t MB = 1ull << 20;
    __bf16* Xbf = (__bf16*)d_ws;                        // 8 MB; reused as Abf
    __bf16* Wbf = (__bf16*)((char*)d_ws + 8 * MB);      // 8 MB (Wq|Wk|Wv|Wo)
    __bf16* Qb  = (__bf16*)((char*)d_ws + 16 * MB);     // 8 MB
    __bf16* Kb  = (__bf16*)((char*)d_ws + 24 * MB);     // 8 MB
    __bf16* Vb  = (__bf16*)((char*)d_ws + 32 * MB);     // 8 MB
    float*  ctab = (float*)((char*)d_ws + 40 * MB);     // 256 KB
    float*  stab = (float*)((char*)d_ws + 41 * MB);     // 256 KB
    __bf16* Abf = Xbf;   // X dead after QKV projection

    // 1. fp32 -> bf16 conversion + RoPE table (fused); 8 floats/thread
    {
        int total = (ROWS * DMODEL + 4 * DMODEL * DMODEL) / 8 + SEQ * 32;
        convert_bf16<<<(total + 255) / 256, 256, 0, stream>>>(
            X, Wq, Wk, Wv, Wo, Xbf, Wbf, ctab, stab);
    }
    // 2. QKV projections with fused RoPE (+Q scale), bf16 out; 128x128 tiles
    //    (round-0 measured-best config)
    {
        dim3 grid(DMODEL / 128, ROWS / 128, 3);
        gemm_qkv_bf<<<grid, 256, 0, stream>>>(Xbf, Wbf, Qb, Kb, Vb, ctab, stab);
    }
    // 3. MFMA sliding-window attention -> bf16 (3 blocks/CU + setprio)
    {
        dim3 grid(SEQ / QTILE, NHEADS, BATCH);
        attn_mfma<<<grid, 256, 0, stream>>>(Qb, Kb, Vb, Abf);
    }
    // 4. Output projection + bias (fp32 out); 64x64 tiles (round-0 verified)
    {
        dim3 grid(DMODEL / 64, ROWS / 64, 1);
        gemm_out_bf<<<grid, 256, 0, stream>>>(Abf, Wbf + 3ull * DMODEL * DMODEL, bo, out);
    }
}